// Round 5
// baseline (371.209 us; speedup 1.0000x reference)
//
#include <hip/hip_runtime.h>

// FloodPath R8: R7 structure + latency/pollution fixes.
//   (a) fc (flood_count) loads software-pipelined one output-iteration ahead,
//       first load hoisted above the dilation loop (hides ~500cy under VALU).
//   (b) nontemporal stores for the 201MB write-once output; nontemporal loads
//       for the read-once streams (pack input, fc) -> packed planes stay
//       L2-resident for flood's 8x-redundant staging reads.
//   Everything else identical to R7: wave-private 64x64 window, 16 shfl
//   dilation steps in registers, bit-sliced counters, wave-private LDS
//   transpose + packed dwordx4 output (197MB ideal write traffic), zero
//   __syncthreads (wave-sync via s_waitcnt lgkmcnt(0)), 8 waves/SIMD.

typedef unsigned long long u64;
typedef float f32x4 __attribute__((ext_vector_type(4)));
typedef float f32x2 __attribute__((ext_vector_type(2)));

#define HH 4096
#define WW 4096
#define WPR 64            // u64 words per image row
#define NSTEPS 16
#define HALO 16
#define IT 32             // interior tile side per wave (64x64 window)

// ---------------- Kernel 1: bitpack ----------------
__global__ __launch_bounds__(256) void pack_kernel(
    const float* __restrict__ flood_input,
    u64* __restrict__ occP, u64* __restrict__ flP)
{
    const int lane = threadIdx.x & 63;
    const int wv   = threadIdx.x >> 6;
    const int r    = blockIdx.x;                  // one image row per block
#pragma unroll
    for (int b = 0; b < 2; ++b) {
        float vx[8], vy[8];
#pragma unroll
        for (int j = 0; j < 8; ++j) {
            const int w = wv * 16 + b * 8 + j;
            const f32x2 v = __builtin_nontemporal_load(
                (const f32x2*)(flood_input +
                                ((size_t)r * WW + (w << 6) + lane) * 2));
            vx[j] = v[0]; vy[j] = v[1];
        }
#pragma unroll
        for (int j = 0; j < 8; ++j) {
            const int w = wv * 16 + b * 8 + j;
            const u64 om = __ballot(vx[j] > 0.5f);
            const u64 fm = __ballot(vy[j] > 0.5f);
            if (lane == 0) {
                occP[(size_t)r * WPR + w] = om;
                flP [(size_t)r * WPR + w] = fm;
            }
        }
    }
}

// ---------------- Kernel 2: flood + count + output ----------------
__global__ __launch_bounds__(256, 8) void flood_kernel(
    const u64* __restrict__ occP, const u64* __restrict__ flP,
    const float* __restrict__ flood_count,
    float* __restrict__ out)
{
    // wave-private transpose planes: [row][occ,f,c0..4] — 7168 B total
    __shared__ u64 plane[4][IT][7];
    // wave-private packed output staging: 8 rows x 104 floats (pad 96->104:
    // row offset = 8 banks; staging writes 2-way, free). 13184 B.
    __shared__ float out2[4][7 * 104 + 96];

    const int tid  = threadIdx.x;
    const int lane = tid & 63;
    const int wv   = tid >> 6;

    const int tile_r0 = blockIdx.y * IT;                 // 0..4064
    const int tile_c0 = blockIdx.x * (4 * IT) + wv * IT; // wave's 32 cols

    // ---- Stage window: rows tile_r0-16+lane, cols tile_c0-16 .. +47.
    const int gr  = tile_r0 - HALO + lane;
    const bool rin = (gr >= 0) & (gr < HH);
    const int s   = tile_c0 - HALO;              // >= -16
    const int q0  = ((s + 64) >> 6) - 1;         // floor(s/64)
    const int sh  = s - (q0 << 6);               // 16 or 48

    const size_t base = (size_t)(rin ? gr : 0) * WPR;
    const int qa = min(max(q0, 0), WPR - 1);
    const int qb = min(max(q0 + 1, 0), WPR - 1);
    u64 o0 = occP[base + qa], o1 = occP[base + qb];
    u64 f0 = flP [base + qa], f1 = flP [base + qb];
    const bool va = rin & (q0 >= 0);
    const bool vb = rin & (q0 + 1 < WPR);
    if (!va) { o0 = ~0ull; f0 = 0ull; }          // OOB => wall, no flood
    if (!vb) { o1 = ~0ull; f1 = 0ull; }
    const u64 occ = (o0 >> sh) | (sh ? (o1 << (64 - sh)) : 0ull);
    u64       f   = (f0 >> sh) | (sh ? (f1 << (64 - sh)) : 0ull);

    // ---- fc prefetch for output iteration 0 (latency hides under dilation).
    const int rsub = lane >> 3;                  // 0..7: row within 8-row chunk
    const int g    = lane & 7;                   // 0..7: 4-px group in row
    const float* fcbase = flood_count + (size_t)(tile_r0 + rsub) * WW
                          + tile_c0 + g * 4;
    f32x4 fc_next = __builtin_nontemporal_load((const f32x4*)fcbase);

    // ---- 16 dilation steps, fully in registers. No barriers.
    const u64 nocc = ~occ;
    u64 c0 = 0, c1 = 0, c2 = 0, c3 = 0, c4 = 0;
#pragma unroll
    for (int it = 0; it < NSTEPS; ++it) {
        u64 up = __shfl_up(f, 1);
        u64 dn = __shfl_down(f, 1);
        if (lane == 0)  up = 0ull;
        if (lane == 63) dn = 0ull;
        f = nocc & (f | (f << 1) | (f >> 1) | up | dn);
        u64 c = f, t;
        t = c0; c0 = t ^ c; c = t & c;
        t = c1; c1 = t ^ c; c = t & c;
        t = c2; c2 = t ^ c; c = t & c;
        t = c3; c3 = t ^ c; c = t & c;
        c4 ^= c;                                 // max 16: no carry out
    }

    // ---- Wave-private transpose: lanes 16..47 hold interior rows.
    if (lane >= HALO && lane < HALO + IT) {
        u64* p = plane[wv][lane - HALO];
        p[0] = occ; p[1] = f;
        p[2] = c0; p[3] = c1; p[4] = c2; p[5] = c3; p[6] = c4;
    }
    asm volatile("s_waitcnt lgkmcnt(0)" ::: "memory");   // wave-sync LDS

    // ---- Output: 4 iterations x 8 rows, wave-private, no barriers.
    const int bit0 = HALO + g * 4;
    for (int t = 0; t < 4; ++t) {
        const f32x4 fc4 = fc_next;
        if (t + 1 < 4)
            fc_next = __builtin_nontemporal_load(
                (const f32x4*)(fcbase + (size_t)(t + 1) * 8 * WW));

        const int irow = t * 8 + rsub;
        const u64* p = plane[wv][irow];
        const u64 ow = p[0], fw = p[1];
        const u64 k0 = p[2], k1 = p[3], k2 = p[4], k3 = p[5], k4 = p[6];

        float v[12];
#pragma unroll
        for (int j = 0; j < 4; ++j) {
            const int bit = bit0 + j;
            int cv = (int)((k0 >> bit) & 1ull)
                   + ((int)((k1 >> bit) & 1ull) << 1)
                   + ((int)((k2 >> bit) & 1ull) << 2)
                   + ((int)((k3 >> bit) & 1ull) << 3)
                   + ((int)((k4 >> bit) & 1ull) << 4);
            v[j*3+0] = (float)((ow >> bit) & 1ull);
            v[j*3+1] = (float)((fw >> bit) & 1ull);
            v[j*3+2] = (float)cv + fc4[j];
        }
        // stage: padded row stride 104 floats (416 B), 16B-aligned per lane
        float* dst = &out2[wv][rsub * 104 + g * 12];
        *(f32x4*)(dst + 0) = (f32x4){v[0], v[1], v[2],  v[3]};
        *(f32x4*)(dst + 4) = (f32x4){v[4], v[5], v[6],  v[7]};
        *(f32x4*)(dst + 8) = (f32x4){v[8], v[9], v[10], v[11]};

        asm volatile("s_waitcnt lgkmcnt(0)" ::: "memory");   // wave-sync LDS

        // readback linearly (logical 8x96 floats), nontemporal dwordx4 stores
#pragma unroll
        for (int st = 0; st < 3; ++st) {
            const int L   = st * 256 + lane * 4;   // 0..767 in 768-float chunk
            const int row = L / 96;                // 0..7
            const int off = L - row * 96;          // 0..95, multiple of 4
            const f32x4 q = *(const f32x4*)(&out2[wv][row * 104 + off]);
            __builtin_nontemporal_store(q,
                (f32x4*)(out + ((size_t)(tile_r0 + t * 8 + row) * WW
                                + tile_c0) * 3 + off));
        }
    }
}

extern "C" void kernel_launch(void* const* d_in, const int* in_sizes, int n_in,
                              void* d_out, int out_size, void* d_ws, size_t ws_size,
                              hipStream_t stream) {
    const float* flood_input = (const float*)d_in[0];  // [4096][4096][2]
    const float* flood_cnt   = (const float*)d_in[1];  // [4096][4096]
    float* out = (float*)d_out;                        // [4096][4096][3]

    u64* occP = (u64*)d_ws;                            // 2 MiB
    u64* flP  = occP + (size_t)HH * WPR;               // 2 MiB

    pack_kernel<<<dim3(HH), dim3(256), 0, stream>>>(flood_input, occP, flP);

    dim3 grid(WW / (4 * IT), HH / IT);                 // 32 x 128 = 4096 blocks
    flood_kernel<<<grid, dim3(256), 0, stream>>>(occP, flP, flood_cnt, out);
}

// Round 6
// 366.940 us; speedup vs baseline: 1.0116x; 1.0116x over previous
//
#include <hip/hip_runtime.h>

// FloodPath R9: R5 structure (best measured: 354) + surgical grafts.
//   vs R5:
//   (1) ONE __syncthreads total (after cross-wave plane transpose). The 4
//       per-iteration barriers were unnecessary: out2[wv] is wave-private ->
//       wave-sync via s_waitcnt lgkmcnt(0) (R6/R7-proven, absmax 0).
//   (2) fc loads software-pipelined one iteration ahead; first load hoisted
//       above the 16-step dilation loop (~640cy VALU hides the latency).
//   (3) Nontemporal stores for the 197MB output stream; nontemporal loads for
//       read-once streams (pack input, fc) -> packed planes stay L2-resident
//       for the 8x-redundant staging reads.
//   Unchanged from R5: wave 64x64 register window (lane=row), 16 shfl
//   dilation steps, bit-sliced counters, cross-wave plane sharing so each
//   wave outputs 8 full-width rows, packed dwordx4 stores (197MB ideal).

typedef unsigned long long u64;
typedef float f32x4 __attribute__((ext_vector_type(4)));
typedef float f32x2 __attribute__((ext_vector_type(2)));

#define HH 4096
#define WW 4096
#define WPR 64            // u64 words per image row
#define NSTEPS 16
#define HALO 16
#define IT 32             // interior tile side per wave (64x64 window)

// ---------------- Kernel 1: bitpack ----------------
__global__ __launch_bounds__(256) void pack_kernel(
    const float* __restrict__ flood_input,
    u64* __restrict__ occP, u64* __restrict__ flP)
{
    const int lane = threadIdx.x & 63;
    const int wv   = threadIdx.x >> 6;
    const int r    = blockIdx.x;                  // one image row per block
#pragma unroll
    for (int b = 0; b < 2; ++b) {
        float vx[8], vy[8];
#pragma unroll
        for (int j = 0; j < 8; ++j) {
            const int w = wv * 16 + b * 8 + j;
            const f32x2 v = __builtin_nontemporal_load(
                (const f32x2*)(flood_input +
                                ((size_t)r * WW + (w << 6) + lane) * 2));
            vx[j] = v[0]; vy[j] = v[1];
        }
#pragma unroll
        for (int j = 0; j < 8; ++j) {
            const int w = wv * 16 + b * 8 + j;
            const u64 om = __ballot(vx[j] > 0.5f);
            const u64 fm = __ballot(vy[j] > 0.5f);
            if (lane == 0) {
                occP[(size_t)r * WPR + w] = om;
                flP [(size_t)r * WPR + w] = fm;
            }
        }
    }
}

// ---------------- Kernel 2: flood + count + output ----------------
__global__ __launch_bounds__(256, 8) void flood_kernel(
    const u64* __restrict__ occP, const u64* __restrict__ flP,
    const float* __restrict__ flood_count,
    float* __restrict__ out)
{
    // cross-wave transpose planes: [wave][interior row][occ,f,c0..4] — 7168 B
    __shared__ u64 plane[4][IT][7];
    // wave-private packed output staging: 2 rows x 128 px x 3 ch — 12288 B
    __shared__ float out2[4][2 * 128 * 3];

    const int tid  = threadIdx.x;
    const int lane = tid & 63;
    const int wv   = tid >> 6;

    const int tile_r0 = blockIdx.y * IT;                 // 0..4064
    const int tile_c0 = blockIdx.x * (4 * IT) + wv * IT; // wave's 32 cols
    const int bc0     = blockIdx.x * (4 * IT);           // block col start

    // ---- Stage window: rows tile_r0-16+lane, cols tile_c0-16 .. +47.
    const int gr  = tile_r0 - HALO + lane;
    const bool rin = (gr >= 0) & (gr < HH);
    const int s   = tile_c0 - HALO;              // >= -16
    const int q0  = ((s + 64) >> 6) - 1;         // floor(s/64)
    const int sh  = s - (q0 << 6);               // 16 or 48

    const size_t base = (size_t)(rin ? gr : 0) * WPR;
    const int qa = min(max(q0, 0), WPR - 1);
    const int qb = min(max(q0 + 1, 0), WPR - 1);
    u64 o0 = occP[base + qa], o1 = occP[base + qb];
    u64 f0 = flP [base + qa], f1 = flP [base + qb];
    const bool va = rin & (q0 >= 0);
    const bool vb = rin & (q0 + 1 < WPR);
    if (!va) { o0 = ~0ull; f0 = 0ull; }          // OOB => wall, no flood
    if (!vb) { o1 = ~0ull; f1 = 0ull; }
    const u64 occ = (o0 >> sh) | (sh ? (o1 << (64 - sh)) : 0ull);
    u64       f   = (f0 >> sh) | (sh ? (f1 << (64 - sh)) : 0ull);

    // ---- fc prefetch for output iteration 0 (hides under dilation VALU).
    const int half = lane >> 5;                  // 0 or 1: row within pair
    const int l32  = lane & 31;
    const int col0 = l32 * 4;                    // block-local col of 4 px
    const float* fcbase = flood_count +
        (size_t)(tile_r0 + wv * 8 + half) * WW + bc0 + col0;
    f32x4 fc_next = __builtin_nontemporal_load((const f32x4*)fcbase);

    // ---- 16 dilation steps, fully in registers. No barriers.
    const u64 nocc = ~occ;
    u64 c0 = 0, c1 = 0, c2 = 0, c3 = 0, c4 = 0;
#pragma unroll
    for (int it = 0; it < NSTEPS; ++it) {
        u64 up = __shfl_up(f, 1);
        u64 dn = __shfl_down(f, 1);
        if (lane == 0)  up = 0ull;
        if (lane == 63) dn = 0ull;
        f = nocc & (f | (f << 1) | (f >> 1) | up | dn);
        u64 c = f, t;
        t = c0; c0 = t ^ c; c = t & c;
        t = c1; c1 = t ^ c; c = t & c;
        t = c2; c2 = t ^ c; c = t & c;
        t = c3; c3 = t ^ c; c = t & c;
        c4 ^= c;                                 // max 16: no carry out
    }

    // ---- Cross-wave transpose: lanes 16..47 hold interior rows.
    if (lane >= HALO && lane < HALO + IT) {
        u64* p = plane[wv][lane - HALO];
        p[0] = occ; p[1] = f;
        p[2] = c0; p[3] = c1; p[4] = c2; p[5] = c3; p[6] = c4;
    }
    __syncthreads();   // the ONE block barrier: planes are read cross-wave

    // ---- Output: wave wv owns interior rows wv*8..wv*8+7, full 128-col
    //      width, as 4 row-pairs. All LDS below is wave-private.
    const int sw   = col0 >> 5;                  // source wave for my 4 px
    const int bit0 = HALO + (col0 & 31);
    for (int t = 0; t < 4; ++t) {
        const f32x4 fc4 = fc_next;
        if (t + 1 < 4)
            fc_next = __builtin_nontemporal_load(
                (const f32x4*)(fcbase + (size_t)(t + 1) * 2 * WW));

        const int rA   = wv * 8 + 2 * t;         // pair's first interior row
        const int irow = rA + half;              // this lane's interior row
        const u64* p = plane[sw][irow];
        const u64 ow = p[0], fw = p[1];
        const u64 k0 = p[2], k1 = p[3], k2 = p[4], k3 = p[5], k4 = p[6];

        float v[12];
#pragma unroll
        for (int j = 0; j < 4; ++j) {
            const int bit = bit0 + j;
            int cv = (int)((k0 >> bit) & 1ull)
                   + ((int)((k1 >> bit) & 1ull) << 1)
                   + ((int)((k2 >> bit) & 1ull) << 2)
                   + ((int)((k3 >> bit) & 1ull) << 3)
                   + ((int)((k4 >> bit) & 1ull) << 4);
            v[j*3+0] = (float)((ow >> bit) & 1ull);
            v[j*3+1] = (float)((fw >> bit) & 1ull);
            v[j*3+2] = (float)cv + fc4[j];
        }
        // stage: byte offset = half*1536 + l32*48 (16B aligned, lane-linear)
        float* dst = &out2[wv][half * 384 + l32 * 12];
        *(f32x4*)(dst + 0) = (f32x4){v[0], v[1], v[2],  v[3]};
        *(f32x4*)(dst + 4) = (f32x4){v[4], v[5], v[6],  v[7]};
        *(f32x4*)(dst + 8) = (f32x4){v[8], v[9], v[10], v[11]};

        asm volatile("s_waitcnt lgkmcnt(0)" ::: "memory");   // wave-private

        // read back linearly, 3 packed nontemporal dwordx4 stores per lane
#pragma unroll
        for (int st = 0; st < 3; ++st) {
            const int L   = st * 256 + lane * 4;   // float idx in 768-float pair
            const int row = (L >= 384) ? 1 : 0;
            const int off = L - row * 384;
            const f32x4 q = *(const f32x4*)(&out2[wv][L]);
            __builtin_nontemporal_store(q,
                (f32x4*)(out + ((size_t)(tile_r0 + rA + row) * WW + bc0) * 3
                         + off));
        }
    }
}

extern "C" void kernel_launch(void* const* d_in, const int* in_sizes, int n_in,
                              void* d_out, int out_size, void* d_ws, size_t ws_size,
                              hipStream_t stream) {
    const float* flood_input = (const float*)d_in[0];  // [4096][4096][2]
    const float* flood_cnt   = (const float*)d_in[1];  // [4096][4096]
    float* out = (float*)d_out;                        // [4096][4096][3]

    u64* occP = (u64*)d_ws;                            // 2 MiB
    u64* flP  = occP + (size_t)HH * WPR;               // 2 MiB

    pack_kernel<<<dim3(HH), dim3(256), 0, stream>>>(flood_input, occP, flP);

    dim3 grid(WW / (4 * IT), HH / IT);                 // 32 x 128 = 4096 blocks
    flood_kernel<<<grid, dim3(256), 0, stream>>>(occP, flP, flood_cnt, out);
}

// Round 7
// 357.718 us; speedup vs baseline: 1.0377x; 1.0258x over previous
//
#include <hip/hip_runtime.h>

// FloodPath R10: exact R5 structure (best measured: 354) + L2 locality fixes.
//   R5 base kept verbatim: wave 64x64 register window (lane=row), 16 shfl
//   dilation steps, bit-sliced counters, cross-wave plane transpose, 4
//   barriered output row-pair iterations, packed dwordx4 stores (197MB ideal).
//   New:
//   (1) Bijective XCD band swizzle: 4096 blocks % 8 == 0; XCD k owns 16
//       contiguous 32-row bands -> per-XCD packed-plane working set ~560KB
//       (was ~4MB = whole L2). The 8x-redundant stride-512B staging gathers
//       become L2 hits (~200cy) instead of HBM misses (~900cy) — R4 counters
//       showed ~33MB of plane re-fetch reaching HBM.
//   (2) Nontemporal for the streams (out stores, fc loads, pack input loads)
//       so they bypass L2 and don't evict the plane set.
//   (3) fc loads software-pipelined one iteration ahead (first hoisted above
//       the dilation loop) — they no longer serialize the barriered waves.

typedef unsigned long long u64;
typedef float f32x4 __attribute__((ext_vector_type(4)));
typedef float f32x2 __attribute__((ext_vector_type(2)));

#define HH 4096
#define WW 4096
#define WPR 64            // u64 words per image row
#define NSTEPS 16
#define HALO 16
#define IT 32             // interior tile side per wave (64x64 window)

// ---------------- Kernel 1: bitpack ----------------
__global__ __launch_bounds__(256) void pack_kernel(
    const float* __restrict__ flood_input,
    u64* __restrict__ occP, u64* __restrict__ flP)
{
    const int lane = threadIdx.x & 63;
    const int wv   = threadIdx.x >> 6;
    const int r    = blockIdx.x;                  // one image row per block
#pragma unroll
    for (int b = 0; b < 2; ++b) {
        float vx[8], vy[8];
#pragma unroll
        for (int j = 0; j < 8; ++j) {
            const int w = wv * 16 + b * 8 + j;
            const f32x2 v = __builtin_nontemporal_load(
                (const f32x2*)(flood_input +
                                ((size_t)r * WW + (w << 6) + lane) * 2));
            vx[j] = v[0]; vy[j] = v[1];
        }
#pragma unroll
        for (int j = 0; j < 8; ++j) {
            const int w = wv * 16 + b * 8 + j;
            const u64 om = __ballot(vx[j] > 0.5f);
            const u64 fm = __ballot(vy[j] > 0.5f);
            if (lane == 0) {
                occP[(size_t)r * WPR + w] = om;
                flP [(size_t)r * WPR + w] = fm;
            }
        }
    }
}

// ---------------- Kernel 2: flood + count + output ----------------
__global__ __launch_bounds__(256, 8) void flood_kernel(
    const u64* __restrict__ occP, const u64* __restrict__ flP,
    const float* __restrict__ flood_count,
    float* __restrict__ out)
{
    // cross-wave transpose planes: [wave][interior row][occ,f,c0..4] — 7168 B
    __shared__ u64 plane[4][IT][7];
    // per-wave packed output staging: 2 rows x 128 px x 3 ch — 12288 B
    __shared__ float out2[4][2 * 128 * 3];

    const int tid  = threadIdx.x;
    const int lane = tid & 63;
    const int wv   = tid >> 6;

    // ---- Bijective XCD band swizzle (4096 blocks, gridDim = 32 x 128).
    //      XCD k (k = wgid & 7 under round-robin dispatch) gets one
    //      contiguous chunk of 512 blocks = 16 full 32-row bands.
    const int wgid = blockIdx.y * 32 + blockIdx.x;   // 0..4095
    const int nl   = (wgid & 7) * 512 + (wgid >> 3); // chunk per XCD
    const int bx   = nl & 31;
    const int by   = nl >> 5;

    const int tile_r0 = by * IT;                     // 0..4064
    const int tile_c0 = bx * (4 * IT) + wv * IT;     // wave's 32 cols
    const int bc0     = bx * (4 * IT);               // block col start

    // ---- Stage window: rows tile_r0-16+lane, cols tile_c0-16 .. +47.
    const int gr  = tile_r0 - HALO + lane;
    const bool rin = (gr >= 0) & (gr < HH);
    const int s   = tile_c0 - HALO;              // >= -16
    const int q0  = ((s + 64) >> 6) - 1;         // floor(s/64)
    const int sh  = s - (q0 << 6);               // 16 or 48

    const size_t base = (size_t)(rin ? gr : 0) * WPR;
    const int qa = min(max(q0, 0), WPR - 1);
    const int qb = min(max(q0 + 1, 0), WPR - 1);
    u64 o0 = occP[base + qa], o1 = occP[base + qb];
    u64 f0 = flP [base + qa], f1 = flP [base + qb];
    const bool va = rin & (q0 >= 0);
    const bool vb = rin & (q0 + 1 < WPR);
    if (!va) { o0 = ~0ull; f0 = 0ull; }          // OOB => wall, no flood
    if (!vb) { o1 = ~0ull; f1 = 0ull; }
    const u64 occ = (o0 >> sh) | (sh ? (o1 << (64 - sh)) : 0ull);
    u64       f   = (f0 >> sh) | (sh ? (f1 << (64 - sh)) : 0ull);

    // ---- fc prefetch for output iteration 0 (hides under dilation VALU).
    const int half = lane >> 5;                  // 0 or 1: row within pair
    const int l32  = lane & 31;
    const int col0 = l32 * 4;                    // block-local col of 4 px
    const float* fcbase = flood_count +
        (size_t)(tile_r0 + wv * 8 + half) * WW + bc0 + col0;
    f32x4 fc_next = __builtin_nontemporal_load((const f32x4*)fcbase);

    // ---- 16 dilation steps, fully in registers. No barriers.
    const u64 nocc = ~occ;
    u64 c0 = 0, c1 = 0, c2 = 0, c3 = 0, c4 = 0;
#pragma unroll
    for (int it = 0; it < NSTEPS; ++it) {
        u64 up = __shfl_up(f, 1);
        u64 dn = __shfl_down(f, 1);
        if (lane == 0)  up = 0ull;
        if (lane == 63) dn = 0ull;
        f = nocc & (f | (f << 1) | (f >> 1) | up | dn);
        u64 c = f, t;
        t = c0; c0 = t ^ c; c = t & c;
        t = c1; c1 = t ^ c; c = t & c;
        t = c2; c2 = t ^ c; c = t & c;
        t = c3; c3 = t ^ c; c = t & c;
        c4 ^= c;                                 // max 16: no carry out
    }

    // ---- Cross-wave transpose: lanes 16..47 hold interior rows.
    if (lane >= HALO && lane < HALO + IT) {
        u64* p = plane[wv][lane - HALO];
        p[0] = occ; p[1] = f;
        p[2] = c0; p[3] = c1; p[4] = c2; p[5] = c3; p[6] = c4;
    }
    __syncthreads();

    // ---- Output: wave wv owns interior rows wv*8..wv*8+7, full 128-col
    //      width, as 4 row-pairs (exact R5 structure, barriers kept).
    const int sw   = col0 >> 5;                  // source wave for my 4 px
    const int bit0 = HALO + (col0 & 31);
    for (int t = 0; t < 4; ++t) {
        const f32x4 fc4 = fc_next;
        if (t + 1 < 4)
            fc_next = __builtin_nontemporal_load(
                (const f32x4*)(fcbase + (size_t)(t + 1) * 2 * WW));

        const int rA   = wv * 8 + 2 * t;         // pair's first interior row
        const int irow = rA + half;              // this lane's interior row
        const u64* p = plane[sw][irow];
        const u64 ow = p[0], fw = p[1];
        const u64 k0 = p[2], k1 = p[3], k2 = p[4], k3 = p[5], k4 = p[6];

        float v[12];
#pragma unroll
        for (int j = 0; j < 4; ++j) {
            const int bit = bit0 + j;
            int cv = (int)((k0 >> bit) & 1ull)
                   + ((int)((k1 >> bit) & 1ull) << 1)
                   + ((int)((k2 >> bit) & 1ull) << 2)
                   + ((int)((k3 >> bit) & 1ull) << 3)
                   + ((int)((k4 >> bit) & 1ull) << 4);
            v[j*3+0] = (float)((ow >> bit) & 1ull);
            v[j*3+1] = (float)((fw >> bit) & 1ull);
            v[j*3+2] = (float)cv + fc4[j];
        }
        // stage: byte offset = half*1536 + l32*48 (16B aligned, lane-linear)
        float* dst = &out2[wv][half * 384 + l32 * 12];
        *(f32x4*)(dst + 0) = (f32x4){v[0], v[1], v[2],  v[3]};
        *(f32x4*)(dst + 4) = (f32x4){v[4], v[5], v[6],  v[7]};
        *(f32x4*)(dst + 8) = (f32x4){v[8], v[9], v[10], v[11]};

        __syncthreads();   // R5's proven lockstep store phase

        // read back linearly, 3 packed nontemporal dwordx4 stores per lane
#pragma unroll
        for (int st = 0; st < 3; ++st) {
            const int L   = st * 256 + lane * 4;   // float idx in 768-float pair
            const int row = (L >= 384) ? 1 : 0;
            const int off = L - row * 384;
            const f32x4 q = *(const f32x4*)(&out2[wv][L]);
            __builtin_nontemporal_store(q,
                (f32x4*)(out + ((size_t)(tile_r0 + rA + row) * WW + bc0) * 3
                         + off));
        }
    }
}

extern "C" void kernel_launch(void* const* d_in, const int* in_sizes, int n_in,
                              void* d_out, int out_size, void* d_ws, size_t ws_size,
                              hipStream_t stream) {
    const float* flood_input = (const float*)d_in[0];  // [4096][4096][2]
    const float* flood_cnt   = (const float*)d_in[1];  // [4096][4096]
    float* out = (float*)d_out;                        // [4096][4096][3]

    u64* occP = (u64*)d_ws;                            // 2 MiB
    u64* flP  = occP + (size_t)HH * WPR;               // 2 MiB

    pack_kernel<<<dim3(HH), dim3(256), 0, stream>>>(flood_input, occP, flP);

    dim3 grid(WW / (4 * IT), HH / IT);                 // 32 x 128 = 4096 blocks
    flood_kernel<<<grid, dim3(256), 0, stream>>>(occP, flP, flood_cnt, out);
}